// Round 10
// baseline (203.312 us; speedup 1.0000x reference)
//
#include <hip/hip_runtime.h>
#include <hip/hip_bf16.h>
#include <math.h>
#include <stdint.h>

#define DIMC   512
#define NHEAD  8
#define HD     64
#define NTOK   1024
#define MTOK   256
#define BSZ    8
#define LN_EPS 1e-5f

typedef __attribute__((ext_vector_type(8))) short  short8v;   // 8 bf16 (4 VGPR)
typedef __attribute__((ext_vector_type(4))) float  f32x4;     // MFMA C/D frag
typedef __attribute__((ext_vector_type(4))) unsigned short us4;

typedef const __attribute__((address_space(1))) unsigned int* gas1_t;
typedef __attribute__((address_space(3))) unsigned int*       las3_t;

__device__ __forceinline__ void gload_lds16(const void* g, void* l) {
    __builtin_amdgcn_global_load_lds((gas1_t)g, (las3_t)l, 16, 0, 0);
}

__device__ __forceinline__ unsigned short f2bf(float f) {
    union { float f; unsigned int u; } v; v.f = f;
    unsigned int u = v.u;
    return (unsigned short)((u + 0x7FFFu + ((u >> 16) & 1u)) >> 16);  // RNE, finite
}

// ---------------------------------------------------------------------------
// prep_all: one dispatch, three roles by block range (all 256 threads).
//   [0, 16384)      : bit-pack mask (4 rows/block, self-probing dtype)
//   [16384, 17024)  : weight convert fp32->bf16 (+ w1 transposed copies)
//   [17024, 19072)  : x prep: x->bf16 AND depthwise conv+LN -> xrb
// ---------------------------------------------------------------------------
#define PM_BLKS 16384
#define CW_BLKS 640
#define PX_BLKS 2048

__global__ __launch_bounds__(256)
void prep_all_kernel(const void* __restrict__ maskp,
                     unsigned long long* __restrict__ packed,
                     const float* __restrict__ qw1, const float* __restrict__ kw1,
                     const float* __restrict__ vw1, const float* __restrict__ qw2,
                     const float* __restrict__ kw2, const float* __restrict__ vw2,
                     const float* __restrict__ pw,  unsigned short* __restrict__ wout,
                     unsigned short* __restrict__ w1t,
                     const float* __restrict__ x,   const float* __restrict__ srw,
                     const float* __restrict__ srb, const float* __restrict__ lng,
                     const float* __restrict__ lnb, unsigned short* __restrict__ xb16,
                     unsigned short* __restrict__ xr)
{
    const int blk = blockIdx.x;
    const int tid = threadIdx.x;

    if (blk < PM_BLKS) {
        // ---------------- mask bit-pack ----------------
        const int w = tid >> 6, lane = tid & 63;
        const unsigned int pw_ = ((const unsigned int*)maskp)[lane];
        const unsigned long long not01 = __ballot(pw_ > 1u);
        const unsigned long long notf  = __ballot(pw_ != 0u && pw_ != 0x3F800000u);
        const int mtype = (not01 == 0ull) ? 0 : ((notf == 0ull) ? 2 : 1);

        const long long row = (long long)blk * 4 + w;   // 65536 rows
        int m0, m1, m2, m3;
        if (mtype == 0) {
            const int4 v = ((const int4*)maskp)[row * 64 + lane];
            m0 = v.x; m1 = v.y; m2 = v.z; m3 = v.w;
        } else if (mtype == 1) {
            const uchar4 v = ((const uchar4*)maskp)[row * 64 + lane];
            m0 = v.x; m1 = v.y; m2 = v.z; m3 = v.w;
        } else {
            const float4 v = ((const float4*)maskp)[row * 64 + lane];
            m0 = (v.x != 0.f); m1 = (v.y != 0.f); m2 = (v.z != 0.f); m3 = (v.w != 0.f);
        }
        const unsigned long long b0 = __ballot(m0 != 0);
        const unsigned long long b1 = __ballot(m1 != 0);
        const unsigned long long b2 = __ballot(m2 != 0);
        const unsigned long long b3 = __ballot(m3 != 0);
        if (lane < 4) {
            const unsigned long long v = lane == 0 ? b0 : lane == 1 ? b1
                                       : lane == 2 ? b2 : b3;
            packed[row * 4 + lane] = v;
        }
        return;
    }

    if (blk < PM_BLKS + CW_BLKS) {
        // ---------------- weight convert ----------------
        const int e = ((blk - PM_BLKS) * 256 + tid) * 4;
        const float* src; int off;
        if      (e < 65536)  { src = qw1; off = e; }
        else if (e < 131072) { src = kw1; off = e - 65536; }
        else if (e < 196608) { src = vw1; off = e - 131072; }
        else if (e < 262144) { src = qw2; off = e - 196608; }
        else if (e < 327680) { src = kw2; off = e - 262144; }
        else if (e < 393216) { src = vw2; off = e - 327680; }
        else                 { src = pw;  off = e - 393216; }
        const float4 v = *(const float4*)(src + off);
        us4 p;
        p[0] = f2bf(v.x); p[1] = f2bf(v.y); p[2] = f2bf(v.z); p[3] = f2bf(v.w);
        *(us4*)(wout + e) = p;
        if (e < 196608) {   // w1 family: also store transposed (j,k) <- (k,j)
            const int mat = e >> 16, rem = e & 65535;
            const int k = rem >> 9, j = rem & 511;
#pragma unroll
            for (int t = 0; t < 4; ++t)
                w1t[mat * 65536 + (j + t) * 128 + k] = p[t];
        }
        return;
    }

    // ---------------- x prep (2 channels / thread) ----------------
    {
        const int bn = blk - (PM_BLKS + CW_BLKS);
        const int b  = bn >> 8;
        const int np = bn & 255;
        const int ho = np >> 4, wo = np & 15;
        const int n00 = (ho * 2) * 32 + wo * 2;

        float y[2];
#pragma unroll
        for (int half = 0; half < 2; ++half) {
            const int c = tid + half * 256;
            const size_t base = ((size_t)b * NTOK) * DIMC + c;
            const float x0 = x[base + (size_t)(n00     ) * DIMC];
            const float x1 = x[base + (size_t)(n00 + 1 ) * DIMC];
            const float x2 = x[base + (size_t)(n00 + 32) * DIMC];
            const float x3 = x[base + (size_t)(n00 + 33) * DIMC];
            xb16[base + (size_t)(n00     ) * DIMC] = f2bf(x0);
            xb16[base + (size_t)(n00 + 1 ) * DIMC] = f2bf(x1);
            xb16[base + (size_t)(n00 + 32) * DIMC] = f2bf(x2);
            xb16[base + (size_t)(n00 + 33) * DIMC] = f2bf(x3);
            const float4 w = *(const float4*)(srw + c * 4);
            y[half] = srb[c] + x0 * w.x + x1 * w.y + x2 * w.z + x3 * w.w;
        }

        float s  = y[0] + y[1];
        float s2 = y[0] * y[0] + y[1] * y[1];
#pragma unroll
        for (int off = 32; off > 0; off >>= 1) {
            s  += __shfl_down(s,  off);
            s2 += __shfl_down(s2, off);
        }
        __shared__ float red[8];
        __shared__ float stats[2];
        const int lane = tid & 63, wid = tid >> 6;
        if (lane == 0) { red[wid] = s; red[4 + wid] = s2; }
        __syncthreads();
        if (tid == 0) {
            float ts = 0.f, ts2 = 0.f;
#pragma unroll
            for (int i = 0; i < 4; ++i) { ts += red[i]; ts2 += red[4 + i]; }
            const float mu  = ts * (1.f / 512.f);
            const float var = ts2 * (1.f / 512.f) - mu * mu;
            stats[0] = mu;
            stats[1] = rsqrtf(var + LN_EPS);
        }
        __syncthreads();
        const float mu = stats[0], rstd = stats[1];
#pragma unroll
        for (int half = 0; half < 2; ++half) {
            const int c = tid + half * 256;
            xr[((size_t)(b * MTOK + np)) * DIMC + c] =
                f2bf((y[half] - mu) * rstd * lng[c] + lnb[c]);
        }
    }
}

// ---------------------------------------------------------------------------
// bf16 MFMA GEMM body: C(M,N) = A(M,K) @ B(N,K)^T. 32x128 tile (r10 retile
// for small-shape parallelism: grids double, 4 blocks/CU), BK=64, 4 waves
// (2x2, each 16x64, acc 1x4). Bijective XCD chunk swizzle (nwg%8==0).
// 2-phase dbuf, counted vmcnt(5) (stage = 1 A-load + 4 B-loads per thread).
// RACE FIX (r9, retained): s_waitcnt lgkmcnt(0) BEFORE the buffer-reuse
// barrier — drains ds_reads into registers before next-tile DMA overwrites.
// OUT_MODE: 0 = f32 (+bias), 1 = bf16,
//           3 = kv split: col<512 -> k row-major; col>=512 -> v per-batch
//               transposed at Cp+1048576 elems.
// BSEL: B += (bm>>9)*65536 (per-512-row-block B select, combine gemm).
// ---------------------------------------------------------------------------
template<int OUT_MODE, int BSEL>
__device__ __forceinline__
void gemm_body(const unsigned short* __restrict__ A,
               const unsigned short* __restrict__ B,
               const float* __restrict__ bias,
               void* __restrict__ Cp, int M, int N, int K, int lb, int nwg,
               unsigned short (*As)[32 * 64], unsigned short (*Bs)[128 * 64])
{
    const int tid  = threadIdx.x;
    const int w    = tid >> 6;
    const int lane = tid & 63;
    const int c16  = lane & 15;
    const int g    = lane >> 4;
    const int wr   = w >> 1, wc = w & 1;      // wave tile: rows wr*16, cols wc*64

    const int L   = (lb & 7) * (nwg >> 3) + (lb >> 3);
    const int gx  = N >> 7;                   // blocks along N
    const size_t bm = (size_t)(L / gx) * 32;
    const size_t bn = (size_t)(L % gx) * 128;
    if (BSEL) B += (bm >> 9) * 65536;

    f32x4 acc[4];
#pragma unroll
    for (int j = 0; j < 4; ++j) acc[j] = (f32x4){0.f, 0.f, 0.f, 0.f};

    const int NT = K >> 6;

    auto stage = [&](int buf, int kt) {
        {   // A tile: 32x64 bf16 = 4 KB -> exactly 1 load/thread
            const int o   = tid * 16;
            const int row = o >> 7;
            const int col = (o & 127) >> 1;
            gload_lds16(A + (bm + row) * K + kt + col, (char*)As[buf] + o);
        }
#pragma unroll
        for (int i = 0; i < 4; ++i) {
            const int o   = (tid + i * 256) * 16;
            const int row = o >> 7;
            const int col = (o & 127) >> 1;
            gload_lds16(B + (bn + row) * K + kt + col, (char*)Bs[buf] + o);
        }
    };

    stage(0, 0);
    int cur = 0;
    for (int t = 0; t < NT; ++t) {
        if (t + 1 < NT) {
            stage(cur ^ 1, (t + 1) * 64);
            asm volatile("s_waitcnt vmcnt(5)" ::: "memory");  // cur's 5 landed
        } else {
            asm volatile("s_waitcnt vmcnt(0)" ::: "memory");
        }
        asm volatile("s_barrier" ::: "memory");
#pragma unroll
        for (int kk = 0; kk < 2; ++kk) {
            short8v a, bb[4];
            a = *(const short8v*)(&As[cur][(wr * 16 + c16) * 64 + kk * 32 + g * 8]);
#pragma unroll
            for (int nf = 0; nf < 4; ++nf)
                bb[nf] = *(const short8v*)(&Bs[cur][(wc * 64 + nf * 16 + c16) * 64 + kk * 32 + g * 8]);
#pragma unroll
            for (int nf = 0; nf < 4; ++nf)
                acc[nf] = __builtin_amdgcn_mfma_f32_16x16x32_bf16(a, bb[nf], acc[nf], 0, 0, 0);
        }
        asm volatile("s_waitcnt lgkmcnt(0)" ::: "memory");  // drain ds_reads (race fix)
        asm volatile("s_barrier" ::: "memory");             // then allow buffer reuse
        cur ^= 1;
    }

    // epilogue: C/D layout col = lane&15, row = (lane>>4)*4 + reg
#pragma unroll
    for (int nf = 0; nf < 4; ++nf) {
        const size_t col = bn + wc * 64 + nf * 16 + c16;
        const size_t r0  = bm + wr * 16 + g * 4;
        if (OUT_MODE == 0) {
            float* C = (float*)Cp;
            const float bv = (bias != nullptr) ? bias[col] : 0.f;
#pragma unroll
            for (int r = 0; r < 4; ++r)
                C[(r0 + r) * N + col] = acc[nf][r] + bv;
        } else if (OUT_MODE == 1) {
            unsigned short* C = (unsigned short*)Cp;
#pragma unroll
            for (int r = 0; r < 4; ++r)
                C[(r0 + r) * N + col] = f2bf(acc[nf][r]);
        } else {
            if (col < 512) {
                unsigned short* Ck = (unsigned short*)Cp;
#pragma unroll
                for (int r = 0; r < 4; ++r)
                    Ck[(r0 + r) * 512 + col] = f2bf(acc[nf][r]);
            } else {
                unsigned short* Cv = (unsigned short*)Cp + 1048576;  // vt16
                const size_t b  = r0 >> 8;
                const size_t m0 = r0 & 255;
                us4 p;
                p[0] = f2bf(acc[nf][0]); p[1] = f2bf(acc[nf][1]);
                p[2] = f2bf(acc[nf][2]); p[3] = f2bf(acc[nf][3]);
                *(us4*)(Cv + (b * 512 + (col - 512)) * 256 + m0) = p;
            }
        }
    }
}

template<int OUT_MODE, int BSEL>
__global__ __launch_bounds__(256)
void gemm_bf16(const unsigned short* __restrict__ A,
               const unsigned short* __restrict__ B,
               const float* __restrict__ bias,
               void* __restrict__ Cp, int M, int N, int K)
{
    __shared__ unsigned short As[2][32 * 64];    // 2 x 4 KB
    __shared__ unsigned short Bs[2][128 * 64];   // 2 x 16 KB
    gemm_body<OUT_MODE, BSEL>(A, B, bias, Cp, M, N, K,
                              (int)blockIdx.x, (int)gridDim.x, As, Bs);
}

// ---------------------------------------------------------------------------
// Fused q + kv GEMM: blocks [0,1024) do q = xb16 @ Wq^T (8192x512x512, bf16
// out); blocks [1024,1536) do [k|v] = xrb @ [Wk;Wv]^T (2048x1024x512, split
// epilogue). Independent outputs; kv blocks fill CUs alongside q blocks.
// ---------------------------------------------------------------------------
__global__ __launch_bounds__(256)
void gemm_qkv(const unsigned short* __restrict__ xb16,
              const unsigned short* __restrict__ xrb,
              const unsigned short* __restrict__ wc16,
              unsigned short* __restrict__ qb16,
              unsigned short* __restrict__ kb16)
{
    __shared__ unsigned short As[2][32 * 64];
    __shared__ unsigned short Bs[2][128 * 64];
    const int b = blockIdx.x;
    if (b < 1024)
        gemm_body<1, 0>(xb16, wc16, nullptr, qb16, 8192, 512, 512, b, 1024, As, Bs);
    else
        gemm_body<3, 0>(xrb, wc16 + 262144, nullptr, kb16, 2048, 1024, 512, b - 1024, 512, As, Bs);
}

// ---------------------------------------------------------------------------
// MFMA attention. Grid: 1024 = qt(16) x bh(64); blockIdx.x = qt*64 + bh so
// the 16 q-tiles of one (b,h) are 64 apart -> same XCD -> K/V L2-resident.
// Block: 256 = 4 waves; wave owns 16 query rows x all 256 keys.
// K h-slice bulk-staged to LDS (pre-swizzled global source); after QK^T
// lgkmcnt(0)+barrier retires K and P tiles overwrite the buffer.
// ---------------------------------------------------------------------------
__global__ __launch_bounds__(256, 4)
void attn_mfma(const unsigned short* __restrict__ qb,
               const unsigned short* __restrict__ kb,
               const unsigned short* __restrict__ vt,
               const unsigned long long* __restrict__ pmask,
               unsigned short* __restrict__ ob)
{
    __shared__ unsigned short Ks[16384];   // 32 KB: K swizzled, then P tiles

    const int tid  = threadIdx.x;
    const int w    = tid >> 6;
    const int lane = tid & 63;
    const int g    = lane >> 4;
    const int c16  = lane & 15;
    const int bh   = blockIdx.x & 63;
    const int qt   = blockIdx.x >> 6;
    const int b    = bh >> 3;
    const int h    = bh & 7;
    const int q0   = qt * 64 + w * 16;

    // ---- stage K h-slice into LDS (swizzled via pre-swizzled global src) ----
    const unsigned short* kgb = kb + ((size_t)b * MTOK) * DIMC + h * HD;
#pragma unroll
    for (int t = 0; t < 8; ++t) {
        const int chunk = t * 256 + w * 64 + lane;        // [0,2048) 16B chunks
        const int o_dma = chunk * 16;                     // linear LDS dest
        const int row   = o_dma >> 7;
        const int o_log = o_dma ^ ((row & 7) << 4);       // involution
        const int slot  = (o_log >> 4) & 7;
        gload_lds16(kgb + (size_t)row * DIMC + slot * 8, (char*)Ks + o_dma);
    }

    // ---- independent global loads (hide under DMA wait) ----
    const size_t prow = (size_t)bh * NTOK + q0 + g * 4;
    unsigned mlo[4], mhi[4];
#pragma unroll
    for (int r = 0; r < 4; ++r) {
        const unsigned long long pm = pmask[(prow + r) * 4 + (c16 & 3)] >> (c16 >> 2);
        mlo[r] = (unsigned)pm;
        mhi[r] = (unsigned)(pm >> 32);
    }
    short8v qf[2];
#pragma unroll
    for (int ks = 0; ks < 2; ++ks)
        qf[ks] = *(const short8v*)(qb + ((size_t)(b * NTOK + q0 + c16)) * DIMC
                                      + h * HD + ks * 32 + g * 8);

    asm volatile("s_waitcnt vmcnt(0)" ::: "memory");
    asm volatile("s_barrier" ::: "memory");               // K tile ready

    // ---- S = Q @ K^T from LDS ----
    f32x4 s[16];
#pragma unroll
    for (int nf = 0; nf < 16; ++nf) s[nf] = (f32x4){0.f, 0.f, 0.f, 0.f};
    __builtin_amdgcn_s_setprio(1);
#pragma unroll
    for (int nf = 0; nf < 16; ++nf) {
        const int kr = nf * 16 + c16;
        const int sw = (kr & 7) << 4;
#pragma unroll
        for (int ks = 0; ks < 2; ++ks) {
            const int o = (kr << 7) + ks * 64 + g * 16;
            const short8v kf = *(const short8v*)((const char*)Ks + (o ^ sw));
            s[nf] = __builtin_amdgcn_mfma_f32_16x16x32_bf16(qf[ks], kf, s[nf], 0, 0, 0);
        }
    }
    __builtin_amdgcn_s_setprio(0);

    // ---- scale + mask (bits from packed words) ----
    const float scale = 0.125f;
#pragma unroll
    for (int nf = 0; nf < 16; ++nf) {
#pragma unroll
        for (int r = 0; r < 4; ++r) {
            const unsigned bit = ((nf < 8 ? (mlo[r] >> (nf * 4))
                                          : (mhi[r] >> ((nf - 8) * 4))) & 1u);
            s[nf][r] = bit ? -INFINITY : s[nf][r] * scale;
        }
    }

    // ---- row softmax (row in 16 lanes of group g, reg r) ----
    float mx[4] = {-1e30f, -1e30f, -1e30f, -1e30f};
#pragma unroll
    for (int nf = 0; nf < 16; ++nf)
#pragma unroll
        for (int r = 0; r < 4; ++r) mx[r] = fmaxf(mx[r], s[nf][r]);
#pragma unroll
    for (int off = 8; off >= 1; off >>= 1)
#pragma unroll
        for (int r = 0; r < 4; ++r) mx[r] = fmaxf(mx[r], __shfl_xor(mx[r], off, 64));

    float sm[4] = {0.f, 0.f, 0.f, 0.f};
#pragma unroll
    for (int nf = 0; nf < 16; ++nf)
#pragma unroll
        for (int r = 0; r < 4; ++r) {
            const float p = __expf(s[nf][r] - mx[r]);
            s[nf][r] = p;
            sm[r] += p;
        }
#pragma unroll
    for (int off = 8; off >= 1; off >>= 1)
#pragma unroll
        for (int r = 0; r < 4; ++r) sm[r] += __shfl_xor(sm[r], off, 64);
    float inv[4];
#pragma unroll
    for (int r = 0; r < 4; ++r) inv[r] = 1.0f / sm[r];

    asm volatile("s_waitcnt lgkmcnt(0)" ::: "memory");  // drain K reads (race fix)
    asm volatile("s_barrier" ::: "memory");             // all waves done reading K

    // ---- P -> bf16 -> LDS (reuse K buffer; per-wave 8KB quadrant) ----
    unsigned short* pw = Ks + w * 4096;
#pragma unroll
    for (int nf = 0; nf < 16; ++nf) {
        const int key = nf * 16 + c16;
#pragma unroll
        for (int r = 0; r < 4; ++r) {
            const int row = g * 4 + r;
            pw[row * 256 + (key ^ ((row & 7) << 3))] = f2bf(s[nf][r] * inv[r]);
        }
    }

    // ---- O = P @ V : A from LDS, B from vt (contiguous keys, L2-hot) ----
    f32x4 o[4];
#pragma unroll
    for (int df = 0; df < 4; ++df) o[df] = (f32x4){0.f, 0.f, 0.f, 0.f};

    const int prw = c16;
    const unsigned short* pr = pw + prw * 256;
    __builtin_amdgcn_s_setprio(1);
#pragma unroll
    for (int kf = 0; kf < 8; ++kf) {
        const int k0 = kf * 32 + g * 8;
        const short8v pa = *(const short8v*)(pr + (k0 ^ ((prw & 7) << 3)));
#pragma unroll
        for (int df = 0; df < 4; ++df) {
            const short8v vf = *(const short8v*)(vt + ((size_t)(b * DIMC + h * HD + df * 16 + c16)) * MTOK + k0);
            o[df] = __builtin_amdgcn_mfma_f32_16x16x32_bf16(pa, vf, o[df], 0, 0, 0);
        }
    }
    __builtin_amdgcn_s_setprio(0);

#pragma unroll
    for (int df = 0; df < 4; ++df)
#pragma unroll
        for (int r = 0; r < 4; ++r)
            ob[((size_t)(b * NTOK + q0 + g * 4 + r)) * DIMC + h * HD + df * 16 + c16] =
                f2bf(o[df][r]);
}

// ---------------------------------------------------------------------------
extern "C" void kernel_launch(void* const* d_in, const int* in_sizes, int n_in,
                              void* d_out, int out_size, void* d_ws, size_t ws_size,
                              hipStream_t stream)
{
    const float* x      = (const float*)d_in[0];
    const void*  mask   = d_in[1];
    const float* q_w1   = (const float*)d_in[2];
    const float* q_w2   = (const float*)d_in[3];
    const float* k_w1   = (const float*)d_in[4];
    const float* k_w2   = (const float*)d_in[5];
    const float* v_w1   = (const float*)d_in[6];
    const float* v_w2   = (const float*)d_in[7];
    const float* sr_w   = (const float*)d_in[8];
    const float* sr_b   = (const float*)d_in[9];
    const float* ln_g   = (const float*)d_in[10];
    const float* ln_b   = (const float*)d_in[11];
    const float* proj_w = (const float*)d_in[12];
    const float* proj_b = (const float*)d_in[13];

    unsigned char* wsb = (unsigned char*)d_ws;
    unsigned short* xb16 = (unsigned short*)(wsb + 0);              // 8MB (dead after q gemm)
    unsigned short* ao16 = (unsigned short*)(wsb + 0);              // 8MB (reuses xb16)
    unsigned short* qb16 = (unsigned short*)(wsb + (8u  << 20));    // 8MB
    unsigned short* xrb  = (unsigned short*)(wsb + (16u << 20));    // 2MB
    unsigned short* w1t  = (unsigned short*)(wsb + (18u << 20));    // 384KB
    unsigned short* kb16 = (unsigned short*)(wsb + (19u << 20));    // 2MB
    unsigned short* vt16 = (unsigned short*)(wsb + (21u << 20));    // 2MB (= kb16 + 1048576 elems, mode-3 contract)
    unsigned short* wts  = (unsigned short*)(wsb + (23u << 20));    // 1.25MB
    unsigned short* wc16 = (unsigned short*)(wsb + (25u << 20));    // 1.5MB (combined 1536x512)
    unsigned long long* pmask = (unsigned long long*)(wsb + (27u << 20)); // 2MB

    const int QW2 = 196608, PW = 393216;

    // one dispatch: mask pack + weight convert + x prep (independent roles)
    prep_all_kernel<<<PM_BLKS + CW_BLKS + PX_BLKS, 256, 0, stream>>>(
        mask, pmask, q_w1, k_w1, v_w1, q_w2, k_w2, v_w2, proj_w, wts, w1t,
        x, sr_w, sr_b, ln_g, ln_b, xb16, xrb);

    // combined low-rank weights: WC(1536x512) = [q_w2;k_w2;v_w2] @ w1 (B select per 512 rows)
    gemm_bf16<1, 1><<<192, 256, 0, stream>>>(wts + QW2, w1t, nullptr, wc16, 1536, 512, 128);

    // q = x @ Wq^T (8192x512x512) and [k|v] = xr @ [Wk;Wv]^T (2048x1024x512), fused
    gemm_qkv<<<1536, 256, 0, stream>>>(xb16, xrb, wc16, qb16, kb16);

    // MFMA attention -> bf16 ao
    attn_mfma<<<1024, 256, 0, stream>>>(qb16, kb16, vt16, pmask, ao16);

    // output projection (+bias), bf16 MFMA, fp32 out
    gemm_bf16<0, 0><<<1024, 256, 0, stream>>>(ao16, wts + PW, proj_b, d_out, 8192, 512, 512);
}

// Round 11
// 197.499 us; speedup vs baseline: 1.0294x; 1.0294x over previous
//
#include <hip/hip_runtime.h>
#include <hip/hip_bf16.h>
#include <math.h>
#include <stdint.h>

#define DIMC   512
#define NHEAD  8
#define HD     64
#define NTOK   1024
#define MTOK   256
#define BSZ    8
#define LN_EPS 1e-5f

typedef __attribute__((ext_vector_type(8))) short  short8v;   // 8 bf16 (4 VGPR)
typedef __attribute__((ext_vector_type(4))) float  f32x4;     // MFMA C/D frag
typedef __attribute__((ext_vector_type(4))) unsigned short us4;

typedef const __attribute__((address_space(1))) unsigned int* gas1_t;
typedef __attribute__((address_space(3))) unsigned int*       las3_t;

__device__ __forceinline__ void gload_lds16(const void* g, void* l) {
    __builtin_amdgcn_global_load_lds((gas1_t)g, (las3_t)l, 16, 0, 0);
}

__device__ __forceinline__ unsigned short f2bf(float f) {
    union { float f; unsigned int u; } v; v.f = f;
    unsigned int u = v.u;
    return (unsigned short)((u + 0x7FFFu + ((u >> 16) & 1u)) >> 16);  // RNE, finite
}

// ---------------------------------------------------------------------------
// prep_all: one dispatch, three roles by block range (all 256 threads).
//   [0, 16384)      : bit-pack mask (4 rows/block, self-probing dtype)
//   [16384, 17024)  : weight convert fp32->bf16 (+ w1 transposed copies)
//   [17024, 19072)  : x prep: x->bf16 AND depthwise conv+LN -> xrb
// ---------------------------------------------------------------------------
#define PM_BLKS 16384
#define CW_BLKS 640
#define PX_BLKS 2048

__global__ __launch_bounds__(256)
void prep_all_kernel(const void* __restrict__ maskp,
                     unsigned long long* __restrict__ packed,
                     const float* __restrict__ qw1, const float* __restrict__ kw1,
                     const float* __restrict__ vw1, const float* __restrict__ qw2,
                     const float* __restrict__ kw2, const float* __restrict__ vw2,
                     const float* __restrict__ pw,  unsigned short* __restrict__ wout,
                     unsigned short* __restrict__ w1t,
                     const float* __restrict__ x,   const float* __restrict__ srw,
                     const float* __restrict__ srb, const float* __restrict__ lng,
                     const float* __restrict__ lnb, unsigned short* __restrict__ xb16,
                     unsigned short* __restrict__ xr)
{
    const int blk = blockIdx.x;
    const int tid = threadIdx.x;

    if (blk < PM_BLKS) {
        // ---------------- mask bit-pack ----------------
        const int w = tid >> 6, lane = tid & 63;
        const unsigned int pw_ = ((const unsigned int*)maskp)[lane];
        const unsigned long long not01 = __ballot(pw_ > 1u);
        const unsigned long long notf  = __ballot(pw_ != 0u && pw_ != 0x3F800000u);
        const int mtype = (not01 == 0ull) ? 0 : ((notf == 0ull) ? 2 : 1);

        const long long row = (long long)blk * 4 + w;   // 65536 rows
        int m0, m1, m2, m3;
        if (mtype == 0) {
            const int4 v = ((const int4*)maskp)[row * 64 + lane];
            m0 = v.x; m1 = v.y; m2 = v.z; m3 = v.w;
        } else if (mtype == 1) {
            const uchar4 v = ((const uchar4*)maskp)[row * 64 + lane];
            m0 = v.x; m1 = v.y; m2 = v.z; m3 = v.w;
        } else {
            const float4 v = ((const float4*)maskp)[row * 64 + lane];
            m0 = (v.x != 0.f); m1 = (v.y != 0.f); m2 = (v.z != 0.f); m3 = (v.w != 0.f);
        }
        const unsigned long long b0 = __ballot(m0 != 0);
        const unsigned long long b1 = __ballot(m1 != 0);
        const unsigned long long b2 = __ballot(m2 != 0);
        const unsigned long long b3 = __ballot(m3 != 0);
        if (lane < 4) {
            const unsigned long long v = lane == 0 ? b0 : lane == 1 ? b1
                                       : lane == 2 ? b2 : b3;
            packed[row * 4 + lane] = v;
        }
        return;
    }

    if (blk < PM_BLKS + CW_BLKS) {
        // ---------------- weight convert ----------------
        const int e = ((blk - PM_BLKS) * 256 + tid) * 4;
        const float* src; int off;
        if      (e < 65536)  { src = qw1; off = e; }
        else if (e < 131072) { src = kw1; off = e - 65536; }
        else if (e < 196608) { src = vw1; off = e - 131072; }
        else if (e < 262144) { src = qw2; off = e - 196608; }
        else if (e < 327680) { src = kw2; off = e - 262144; }
        else if (e < 393216) { src = vw2; off = e - 327680; }
        else                 { src = pw;  off = e - 393216; }
        const float4 v = *(const float4*)(src + off);
        us4 p;
        p[0] = f2bf(v.x); p[1] = f2bf(v.y); p[2] = f2bf(v.z); p[3] = f2bf(v.w);
        *(us4*)(wout + e) = p;
        if (e < 196608) {   // w1 family: also store transposed (j,k) <- (k,j)
            const int mat = e >> 16, rem = e & 65535;
            const int k = rem >> 9, j = rem & 511;
#pragma unroll
            for (int t = 0; t < 4; ++t)
                w1t[mat * 65536 + (j + t) * 128 + k] = p[t];
        }
        return;
    }

    // ---------------- x prep (2 channels / thread) ----------------
    {
        const int bn = blk - (PM_BLKS + CW_BLKS);
        const int b  = bn >> 8;
        const int np = bn & 255;
        const int ho = np >> 4, wo = np & 15;
        const int n00 = (ho * 2) * 32 + wo * 2;

        float y[2];
#pragma unroll
        for (int half = 0; half < 2; ++half) {
            const int c = tid + half * 256;
            const size_t base = ((size_t)b * NTOK) * DIMC + c;
            const float x0 = x[base + (size_t)(n00     ) * DIMC];
            const float x1 = x[base + (size_t)(n00 + 1 ) * DIMC];
            const float x2 = x[base + (size_t)(n00 + 32) * DIMC];
            const float x3 = x[base + (size_t)(n00 + 33) * DIMC];
            xb16[base + (size_t)(n00     ) * DIMC] = f2bf(x0);
            xb16[base + (size_t)(n00 + 1 ) * DIMC] = f2bf(x1);
            xb16[base + (size_t)(n00 + 32) * DIMC] = f2bf(x2);
            xb16[base + (size_t)(n00 + 33) * DIMC] = f2bf(x3);
            const float4 w = *(const float4*)(srw + c * 4);
            y[half] = srb[c] + x0 * w.x + x1 * w.y + x2 * w.z + x3 * w.w;
        }

        float s  = y[0] + y[1];
        float s2 = y[0] * y[0] + y[1] * y[1];
#pragma unroll
        for (int off = 32; off > 0; off >>= 1) {
            s  += __shfl_down(s,  off);
            s2 += __shfl_down(s2, off);
        }
        __shared__ float red[8];
        __shared__ float stats[2];
        const int lane = tid & 63, wid = tid >> 6;
        if (lane == 0) { red[wid] = s; red[4 + wid] = s2; }
        __syncthreads();
        if (tid == 0) {
            float ts = 0.f, ts2 = 0.f;
#pragma unroll
            for (int i = 0; i < 4; ++i) { ts += red[i]; ts2 += red[4 + i]; }
            const float mu  = ts * (1.f / 512.f);
            const float var = ts2 * (1.f / 512.f) - mu * mu;
            stats[0] = mu;
            stats[1] = rsqrtf(var + LN_EPS);
        }
        __syncthreads();
        const float mu = stats[0], rstd = stats[1];
#pragma unroll
        for (int half = 0; half < 2; ++half) {
            const int c = tid + half * 256;
            xr[((size_t)(b * MTOK + np)) * DIMC + c] =
                f2bf((y[half] - mu) * rstd * lng[c] + lnb[c]);
        }
    }
}

// ---------------------------------------------------------------------------
// bf16 MFMA GEMM body: C(M,N) = A(M,K) @ B(N,K)^T. 64x128 tile, BK=64,
// 4 waves (2x2, each 32x64). Bijective XCD chunk swizzle (nwg%8==0).
// 2-phase dbuf, counted vmcnt(6). Measured local optimum: 128^2 (r6) 220us,
// 64x128 (r7-r9) 199us, 32x128 (r10) 203us -> 64x128 kept.
// RACE FIX (r9): s_waitcnt lgkmcnt(0) BEFORE the buffer-reuse barrier —
// drains this wave's ds_reads into registers before any wave's next-tile
// global_load_lds DMA overwrites the buffer (rule #18 class hazard).
// OUT_MODE: 0 = f32 (+bias), 1 = bf16,
//           3 = kv split: col<512 -> k row-major; col>=512 -> v per-batch
//               transposed at Cp+1048576 elems.
// BSEL: B += (bm>>9)*65536 (per-512-row-block B select, combine gemm).
// ---------------------------------------------------------------------------
template<int OUT_MODE, int BSEL>
__device__ __forceinline__
void gemm_body(const unsigned short* __restrict__ A,
               const unsigned short* __restrict__ B,
               const float* __restrict__ bias,
               void* __restrict__ Cp, int M, int N, int K, int lb, int nwg,
               unsigned short (*As)[64 * 64], unsigned short (*Bs)[128 * 64])
{
    const int tid  = threadIdx.x;
    const int w    = tid >> 6;
    const int lane = tid & 63;
    const int c16  = lane & 15;
    const int g    = lane >> 4;
    const int wr   = w >> 1, wc = w & 1;      // wave tile: rows wr*32, cols wc*64

    const int L   = (lb & 7) * (nwg >> 3) + (lb >> 3);
    const int gx  = N >> 7;                   // blocks along N
    const size_t bm = (size_t)(L / gx) * 64;
    const size_t bn = (size_t)(L % gx) * 128;
    if (BSEL) B += (bm >> 9) * 65536;

    f32x4 acc[2][4];
#pragma unroll
    for (int i = 0; i < 2; ++i)
#pragma unroll
        for (int j = 0; j < 4; ++j) acc[i][j] = (f32x4){0.f, 0.f, 0.f, 0.f};

    const int NT = K >> 6;

    auto stage = [&](int buf, int kt) {
#pragma unroll
        for (int i = 0; i < 2; ++i) {
            const int o   = (tid + i * 256) * 16;
            const int row = o >> 7;
            const int col = (o & 127) >> 1;
            gload_lds16(A + (bm + row) * K + kt + col, (char*)As[buf] + o);
        }
#pragma unroll
        for (int i = 0; i < 4; ++i) {
            const int o   = (tid + i * 256) * 16;
            const int row = o >> 7;
            const int col = (o & 127) >> 1;
            gload_lds16(B + (bn + row) * K + kt + col, (char*)Bs[buf] + o);
        }
    };

    stage(0, 0);
    int cur = 0;
    for (int t = 0; t < NT; ++t) {
        if (t + 1 < NT) {
            stage(cur ^ 1, (t + 1) * 64);
            asm volatile("s_waitcnt vmcnt(6)" ::: "memory");  // cur's 6 landed
        } else {
            asm volatile("s_waitcnt vmcnt(0)" ::: "memory");
        }
        asm volatile("s_barrier" ::: "memory");
#pragma unroll
        for (int kk = 0; kk < 2; ++kk) {
            short8v a[2], bb[4];
#pragma unroll
            for (int mf = 0; mf < 2; ++mf)
                a[mf] = *(const short8v*)(&As[cur][(wr * 32 + mf * 16 + c16) * 64 + kk * 32 + g * 8]);
#pragma unroll
            for (int nf = 0; nf < 4; ++nf)
                bb[nf] = *(const short8v*)(&Bs[cur][(wc * 64 + nf * 16 + c16) * 64 + kk * 32 + g * 8]);
#pragma unroll
            for (int mf = 0; mf < 2; ++mf)
#pragma unroll
                for (int nf = 0; nf < 4; ++nf)
                    acc[mf][nf] = __builtin_amdgcn_mfma_f32_16x16x32_bf16(a[mf], bb[nf], acc[mf][nf], 0, 0, 0);
        }
        asm volatile("s_waitcnt lgkmcnt(0)" ::: "memory");  // drain ds_reads (race fix)
        asm volatile("s_barrier" ::: "memory");             // then allow buffer reuse
        cur ^= 1;
    }

    // epilogue: C/D layout col = lane&15, row = (lane>>4)*4 + reg
#pragma unroll
    for (int mf = 0; mf < 2; ++mf) {
#pragma unroll
        for (int nf = 0; nf < 4; ++nf) {
            const size_t col = bn + wc * 64 + nf * 16 + c16;
            const size_t r0  = bm + wr * 32 + mf * 16 + g * 4;
            if (OUT_MODE == 0) {
                float* C = (float*)Cp;
                const float bv = (bias != nullptr) ? bias[col] : 0.f;
#pragma unroll
                for (int r = 0; r < 4; ++r)
                    C[(r0 + r) * N + col] = acc[mf][nf][r] + bv;
            } else if (OUT_MODE == 1) {
                unsigned short* C = (unsigned short*)Cp;
#pragma unroll
                for (int r = 0; r < 4; ++r)
                    C[(r0 + r) * N + col] = f2bf(acc[mf][nf][r]);
            } else {
                if (col < 512) {
                    unsigned short* Ck = (unsigned short*)Cp;
#pragma unroll
                    for (int r = 0; r < 4; ++r)
                        Ck[(r0 + r) * 512 + col] = f2bf(acc[mf][nf][r]);
                } else {
                    unsigned short* Cv = (unsigned short*)Cp + 1048576;  // vt16
                    const size_t b  = r0 >> 8;
                    const size_t m0 = r0 & 255;
                    us4 p;
                    p[0] = f2bf(acc[mf][nf][0]); p[1] = f2bf(acc[mf][nf][1]);
                    p[2] = f2bf(acc[mf][nf][2]); p[3] = f2bf(acc[mf][nf][3]);
                    *(us4*)(Cv + (b * 512 + (col - 512)) * 256 + m0) = p;
                }
            }
        }
    }
}

template<int OUT_MODE, int BSEL>
__global__ __launch_bounds__(256)
void gemm_bf16(const unsigned short* __restrict__ A,
               const unsigned short* __restrict__ B,
               const float* __restrict__ bias,
               void* __restrict__ Cp, int M, int N, int K)
{
    __shared__ unsigned short As[2][64 * 64];    // 2 x 8 KB
    __shared__ unsigned short Bs[2][128 * 64];   // 2 x 16 KB
    gemm_body<OUT_MODE, BSEL>(A, B, bias, Cp, M, N, K,
                              (int)blockIdx.x, (int)gridDim.x, As, Bs);
}

// ---------------------------------------------------------------------------
// Fused q + kv GEMM: blocks [0,512) do q = xb16 @ Wq^T (8192x512x512, bf16
// out); blocks [512,768) do [k|v] = xrb @ [Wk;Wv]^T (2048x1024x512, split
// epilogue). Independent outputs; kv blocks fill CUs alongside q blocks.
// ---------------------------------------------------------------------------
__global__ __launch_bounds__(256)
void gemm_qkv(const unsigned short* __restrict__ xb16,
              const unsigned short* __restrict__ xrb,
              const unsigned short* __restrict__ wc16,
              unsigned short* __restrict__ qb16,
              unsigned short* __restrict__ kb16)
{
    __shared__ unsigned short As[2][64 * 64];
    __shared__ unsigned short Bs[2][128 * 64];
    const int b = blockIdx.x;
    if (b < 512)
        gemm_body<1, 0>(xb16, wc16, nullptr, qb16, 8192, 512, 512, b, 512, As, Bs);
    else
        gemm_body<3, 0>(xrb, wc16 + 262144, nullptr, kb16, 2048, 1024, 512, b - 512, 256, As, Bs);
}

// ---------------------------------------------------------------------------
// MFMA attention. Grid: 1024 = qt(16) x bh(64); blockIdx.x = qt*64 + bh so
// the 16 q-tiles of one (b,h) are 64 apart -> same XCD -> K/V L2-resident.
// Block: 256 = 4 waves; wave owns 16 query rows x all 256 keys.
// K h-slice bulk-staged to LDS (pre-swizzled global source); after QK^T
// lgkmcnt(0)+barrier retires K and P tiles overwrite the buffer.
// ---------------------------------------------------------------------------
__global__ __launch_bounds__(256, 4)
void attn_mfma(const unsigned short* __restrict__ qb,
               const unsigned short* __restrict__ kb,
               const unsigned short* __restrict__ vt,
               const unsigned long long* __restrict__ pmask,
               unsigned short* __restrict__ ob)
{
    __shared__ unsigned short Ks[16384];   // 32 KB: K swizzled, then P tiles

    const int tid  = threadIdx.x;
    const int w    = tid >> 6;
    const int lane = tid & 63;
    const int g    = lane >> 4;
    const int c16  = lane & 15;
    const int bh   = blockIdx.x & 63;
    const int qt   = blockIdx.x >> 6;
    const int b    = bh >> 3;
    const int h    = bh & 7;
    const int q0   = qt * 64 + w * 16;

    // ---- stage K h-slice into LDS (swizzled via pre-swizzled global src) ----
    const unsigned short* kgb = kb + ((size_t)b * MTOK) * DIMC + h * HD;
#pragma unroll
    for (int t = 0; t < 8; ++t) {
        const int chunk = t * 256 + w * 64 + lane;        // [0,2048) 16B chunks
        const int o_dma = chunk * 16;                     // linear LDS dest
        const int row   = o_dma >> 7;
        const int o_log = o_dma ^ ((row & 7) << 4);       // involution
        const int slot  = (o_log >> 4) & 7;
        gload_lds16(kgb + (size_t)row * DIMC + slot * 8, (char*)Ks + o_dma);
    }

    // ---- independent global loads (hide under DMA wait) ----
    const size_t prow = (size_t)bh * NTOK + q0 + g * 4;
    unsigned mlo[4], mhi[4];
#pragma unroll
    for (int r = 0; r < 4; ++r) {
        const unsigned long long pm = pmask[(prow + r) * 4 + (c16 & 3)] >> (c16 >> 2);
        mlo[r] = (unsigned)pm;
        mhi[r] = (unsigned)(pm >> 32);
    }
    short8v qf[2];
#pragma unroll
    for (int ks = 0; ks < 2; ++ks)
        qf[ks] = *(const short8v*)(qb + ((size_t)(b * NTOK + q0 + c16)) * DIMC
                                      + h * HD + ks * 32 + g * 8);

    asm volatile("s_waitcnt vmcnt(0)" ::: "memory");
    asm volatile("s_barrier" ::: "memory");               // K tile ready

    // ---- S = Q @ K^T from LDS ----
    f32x4 s[16];
#pragma unroll
    for (int nf = 0; nf < 16; ++nf) s[nf] = (f32x4){0.f, 0.f, 0.f, 0.f};
    __builtin_amdgcn_s_setprio(1);
#pragma unroll
    for (int nf = 0; nf < 16; ++nf) {
        const int kr = nf * 16 + c16;
        const int sw = (kr & 7) << 4;
#pragma unroll
        for (int ks = 0; ks < 2; ++ks) {
            const int o = (kr << 7) + ks * 64 + g * 16;
            const short8v kf = *(const short8v*)((const char*)Ks + (o ^ sw));
            s[nf] = __builtin_amdgcn_mfma_f32_16x16x32_bf16(qf[ks], kf, s[nf], 0, 0, 0);
        }
    }
    __builtin_amdgcn_s_setprio(0);

    // ---- scale + mask (bits from packed words) ----
    const float scale = 0.125f;
#pragma unroll
    for (int nf = 0; nf < 16; ++nf) {
#pragma unroll
        for (int r = 0; r < 4; ++r) {
            const unsigned bit = ((nf < 8 ? (mlo[r] >> (nf * 4))
                                          : (mhi[r] >> ((nf - 8) * 4))) & 1u);
            s[nf][r] = bit ? -INFINITY : s[nf][r] * scale;
        }
    }

    // ---- row softmax (row in 16 lanes of group g, reg r) ----
    float mx[4] = {-1e30f, -1e30f, -1e30f, -1e30f};
#pragma unroll
    for (int nf = 0; nf < 16; ++nf)
#pragma unroll
        for (int r = 0; r < 4; ++r) mx[r] = fmaxf(mx[r], s[nf][r]);
#pragma unroll
    for (int off = 8; off >= 1; off >>= 1)
#pragma unroll
        for (int r = 0; r < 4; ++r) mx[r] = fmaxf(mx[r], __shfl_xor(mx[r], off, 64));

    float sm[4] = {0.f, 0.f, 0.f, 0.f};
#pragma unroll
    for (int nf = 0; nf < 16; ++nf)
#pragma unroll
        for (int r = 0; r < 4; ++r) {
            const float p = __expf(s[nf][r] - mx[r]);
            s[nf][r] = p;
            sm[r] += p;
        }
#pragma unroll
    for (int off = 8; off >= 1; off >>= 1)
#pragma unroll
        for (int r = 0; r < 4; ++r) sm[r] += __shfl_xor(sm[r], off, 64);
    float inv[4];
#pragma unroll
    for (int r = 0; r < 4; ++r) inv[r] = 1.0f / sm[r];

    asm volatile("s_waitcnt lgkmcnt(0)" ::: "memory");  // drain K reads (race fix)
    asm volatile("s_barrier" ::: "memory");             // all waves done reading K

    // ---- P -> bf16 -> LDS (reuse K buffer; per-wave 8KB quadrant) ----
    unsigned short* pw = Ks + w * 4096;
#pragma unroll
    for (int nf = 0; nf < 16; ++nf) {
        const int key = nf * 16 + c16;
#pragma unroll
        for (int r = 0; r < 4; ++r) {
            const int row = g * 4 + r;
            pw[row * 256 + (key ^ ((row & 7) << 3))] = f2bf(s[nf][r] * inv[r]);
        }
    }

    // ---- O = P @ V : A from LDS, B from vt (contiguous keys, L2-hot) ----
    f32x4 o[4];
#pragma unroll
    for (int df = 0; df < 4; ++df) o[df] = (f32x4){0.f, 0.f, 0.f, 0.f};

    const int prw = c16;
    const unsigned short* pr = pw + prw * 256;
    __builtin_amdgcn_s_setprio(1);
#pragma unroll
    for (int kf = 0; kf < 8; ++kf) {
        const int k0 = kf * 32 + g * 8;
        const short8v pa = *(const short8v*)(pr + (k0 ^ ((prw & 7) << 3)));
#pragma unroll
        for (int df = 0; df < 4; ++df) {
            const short8v vf = *(const short8v*)(vt + ((size_t)(b * DIMC + h * HD + df * 16 + c16)) * MTOK + k0);
            o[df] = __builtin_amdgcn_mfma_f32_16x16x32_bf16(pa, vf, o[df], 0, 0, 0);
        }
    }
    __builtin_amdgcn_s_setprio(0);

#pragma unroll
    for (int df = 0; df < 4; ++df)
#pragma unroll
        for (int r = 0; r < 4; ++r)
            ob[((size_t)(b * NTOK + q0 + g * 4 + r)) * DIMC + h * HD + df * 16 + c16] =
                f2bf(o[df][r]);
}

// ---------------------------------------------------------------------------
extern "C" void kernel_launch(void* const* d_in, const int* in_sizes, int n_in,
                              void* d_out, int out_size, void* d_ws, size_t ws_size,
                              hipStream_t stream)
{
    const float* x      = (const float*)d_in[0];
    const void*  mask   = d_in[1];
    const float* q_w1   = (const float*)d_in[2];
    const float* q_w2   = (const float*)d_in[3];
    const float* k_w1   = (const float*)d_in[4];
    const float* k_w2   = (const float*)d_in[5];
    const float* v_w1   = (const float*)d_in[6];
    const float* v_w2   = (const float*)d_in[7];
    const float* sr_w   = (const float*)d_in[8];
    const float* sr_b   = (const float*)d_in[9];
    const float* ln_g   = (const float*)d_in[10];
    const float* ln_b   = (const float*)d_in[11];
    const float* proj_w = (const float*)d_in[12];
    const float* proj_b = (const float*)d_in[13];

    unsigned char* wsb = (unsigned char*)d_ws;
    unsigned short* xb16 = (unsigned short*)(wsb + 0);              // 8MB (dead after q gemm)
    unsigned short* ao16 = (unsigned short*)(wsb + 0);              // 8MB (reuses xb16)
    unsigned short* qb16 = (unsigned short*)(wsb + (8u  << 20));    // 8MB
    unsigned short* xrb  = (unsigned short*)(wsb + (16u << 20));    // 2MB
    unsigned short* w1t  = (unsigned short*)(wsb + (18u << 20));    // 384KB
    unsigned short* kb16 = (unsigned short*)(wsb + (19u << 20));    // 2MB
    unsigned short* vt16 = (unsigned short*)(wsb + (21u << 20));    // 2MB (= kb16 + 1048576 elems, mode-3 contract)
    unsigned short* wts  = (unsigned short*)(wsb + (23u << 20));    // 1.25MB
    unsigned short* wc16 = (unsigned short*)(wsb + (25u << 20));    // 1.5MB (combined 1536x512)
    unsigned long long* pmask = (unsigned long long*)(wsb + (27u << 20)); // 2MB

    const int QW2 = 196608, PW = 393216;

    // one dispatch: mask pack + weight convert + x prep (independent roles)
    prep_all_kernel<<<PM_BLKS + CW_BLKS + PX_BLKS, 256, 0, stream>>>(
        mask, pmask, q_w1, k_w1, v_w1, q_w2, k_w2, v_w2, proj_w, wts, w1t,
        x, sr_w, sr_b, ln_g, ln_b, xb16, xrb);

    // combined low-rank weights: WC(1536x512) = [q_w2;k_w2;v_w2] @ w1 (B select per 512 rows)
    gemm_bf16<1, 1><<<96, 256, 0, stream>>>(wts + QW2, w1t, nullptr, wc16, 1536, 512, 128);

    // q = x @ Wq^T (8192x512x512) and [k|v] = xr @ [Wk;Wv]^T (2048x1024x512), fused
    gemm_qkv<<<768, 256, 0, stream>>>(xb16, xrb, wc16, qb16, kb16);

    // MFMA attention -> bf16 ao
    attn_mfma<<<1024, 256, 0, stream>>>(qb16, kb16, vt16, pmask, ao16);

    // output projection (+bias), bf16 MFMA, fp32 out
    gemm_bf16<0, 0><<<512, 256, 0, stream>>>(ao16, wts + PW, proj_b, d_out, 8192, 512, 512);
}